// Round 1
// baseline (514.531 us; speedup 1.0000x reference)
//
#include <hip/hip_runtime.h>

#define B_   1024
#define A_   64
#define G_   31
#define W_   8
#define H_   512
#define L_   2
#define S_   32
#define DK_  32
#define K3H_ 1536

typedef short short8 __attribute__((ext_vector_type(8)));
typedef float floatx4 __attribute__((ext_vector_type(4)));

__device__ __forceinline__ float bf2f(unsigned short u){
  union { unsigned int i; float f; } x; x.i = ((unsigned int)u) << 16; return x.f;
}
__device__ __forceinline__ unsigned short f2bf(float f){
  union { float f; unsigned int i; } x; x.f = f;
  unsigned int u = x.i;
  return (unsigned short)((u + 0x7FFFu + ((u >> 16) & 1u)) >> 16);
}
__device__ __forceinline__ void gl_lds16(const unsigned short* g, unsigned short* l){
  __builtin_amdgcn_global_load_lds((const __attribute__((address_space(1))) unsigned int*)g,
                                   (__attribute__((address_space(3))) unsigned int*)l, 16, 0, 0);
}

// ---------------- K0: convert/transpose weights to bf16 ----------------
// lr_wT[n(512)][k(1536)], qkvT[l][p][n(32)][k(512)], denseT[l][n(512)][k(32)], lin_wT[n(512)][k(512)]
__global__ __launch_bounds__(256) void prep_weights(
    const float* __restrict__ lr_w, const float* __restrict__ wq_w, const float* __restrict__ wk_w,
    const float* __restrict__ wv_w, const float* __restrict__ dense_w, const float* __restrict__ lin_w,
    unsigned short* __restrict__ lr_wT, unsigned short* __restrict__ qkvT,
    unsigned short* __restrict__ denseT, unsigned short* __restrict__ lin_wT){
  int i = blockIdx.x * 256 + threadIdx.x;
  if (i < 786432){                       // lr_wT
    int n = i / K3H_, k = i % K3H_;
    lr_wT[i] = f2bf(lr_w[(size_t)k * H_ + n]);
    return;
  }
  i -= 786432;
  if (i < 98304){                        // qkvT
    int k = i & 511; int t = i >> 9; int n = t & 31; int u = t >> 5;
    int p = u % 3, l = u / 3;
    const float* src = (p == 0) ? wq_w : (p == 1) ? wk_w : wv_w;
    qkvT[((size_t)((l*3+p)*S_ + n)) * H_ + k] = f2bf(src[((size_t)(l*H_ + k)) * DK_ + n]);
    return;
  }
  i -= 98304;
  if (i < 32768){                        // denseT
    int k = i & 31; int t = i >> 5; int n = t & 511; int l = t >> 9;
    denseT[((size_t)(l*H_ + n)) * DK_ + k] = f2bf(dense_w[((size_t)(l*DK_ + k)) * H_ + n]);
    return;
  }
  i -= 32768;                            // lin_wT
  int n = i >> 9, k = i & 511;
  lin_wT[(size_t)n * H_ + k] = f2bf(lin_w[(size_t)k * H_ + n]);
}

// ---------------- K1: build brics rows (gather sum/max + f_group, fg for s=0) ----------------
__global__ __launch_bounds__(64) void build_brics(
    const float* __restrict__ f_atom, const float* __restrict__ f_group,
    const float* __restrict__ fg, const int* __restrict__ mapping,
    unsigned short* __restrict__ brics){
  int blk = blockIdx.x;           // b*32 + s
  int b = blk >> 5, s = blk & 31;
  int t = threadIdx.x;
  unsigned short* out = brics + (size_t)blk * K3H_;
  if (s == 0){
    for (int k = t; k < K3H_; k += 64) out[k] = f2bf(fg[k]);
    return;
  }
  int g = s - 1;
  const int* mp = mapping + ((size_t)(b * G_ + g)) * W_;
  int c0 = t * 8;
  float sum[8], mx[8];
  #pragma unroll
  for (int j = 0; j < 8; ++j){ sum[j] = 0.f; mx[j] = -3.4e38f; }
  for (int w = 0; w < W_; ++w){
    int idx = mp[w];
    if (idx == 0){
      #pragma unroll
      for (int j = 0; j < 8; ++j) mx[j] = fmaxf(mx[j], 0.f);
    } else {
      const float* row = f_atom + ((size_t)(b * A_ + idx - 1)) * H_ + c0;
      float4 v0 = *(const float4*)row;
      float4 v1 = *(const float4*)(row + 4);
      float v[8] = {v0.x,v0.y,v0.z,v0.w,v1.x,v1.y,v1.z,v1.w};
      #pragma unroll
      for (int j = 0; j < 8; ++j){ sum[j] += v[j]; mx[j] = fmaxf(mx[j], v[j]); }
    }
  }
  const float* grow = f_group + ((size_t)(b * G_ + g)) * H_ + c0;
  float4 g0 = *(const float4*)grow;
  float4 g1 = *(const float4*)(grow + 4);
  float gv[8] = {g0.x,g0.y,g0.z,g0.w,g1.x,g1.y,g1.z,g1.w};
  unsigned short tmp[8] __attribute__((aligned(16)));
  #pragma unroll
  for (int j = 0; j < 8; ++j) tmp[j] = f2bf(sum[j]);
  *(uint4*)(out + c0) = *(const uint4*)tmp;
  #pragma unroll
  for (int j = 0; j < 8; ++j) tmp[j] = f2bf(mx[j]);
  *(uint4*)(out + 512 + c0) = *(const uint4*)tmp;
  #pragma unroll
  for (int j = 0; j < 8; ++j) tmp[j] = f2bf(gv[j]);
  *(uint4*)(out + 1024 + c0) = *(const uint4*)tmp;
}

// ---------------- K2: f_frag = relu(brics @ lr_w + lr_b), bf16 MFMA 128x128 tile ----------------
__global__ __launch_bounds__(256) void gemm_frag(
    const unsigned short* __restrict__ brics, const unsigned short* __restrict__ wT,
    const float* __restrict__ lr_b, unsigned short* __restrict__ f_frag){
  __shared__ __align__(16) unsigned short As[128*32];
  __shared__ __align__(16) unsigned short Bs[128*32];
  int tid = threadIdx.x;
  int bx = blockIdx.x;
  int mtile = bx >> 2, ntile = bx & 3;
  int rowStart = mtile * 128, colStart = ntile * 128;
  int lane = tid & 63, wave = tid >> 6;
  int m16 = lane & 15, quad = lane >> 4;
  int wm = wave >> 1, wn = wave & 1;
  floatx4 acc[4][4];
  #pragma unroll
  for (int i = 0; i < 4; ++i)
    #pragma unroll
    for (int j = 0; j < 4; ++j) acc[i][j] = (floatx4){0.f,0.f,0.f,0.f};

  int r0 = tid >> 2, c0 = tid & 3;          // slot tid
  int r1 = (tid + 256) >> 2;                // slot tid+256 (same chunk c0)
  for (int kt = 0; kt < K3H_/32; ++kt){
    const unsigned short* gA0 = brics + (size_t)(rowStart + r0) * K3H_ + kt*32 + c0*8;
    const unsigned short* gA1 = brics + (size_t)(rowStart + r1) * K3H_ + kt*32 + c0*8;
    const unsigned short* gB0 = wT + (size_t)(colStart + r0) * K3H_ + kt*32 + c0*8;
    const unsigned short* gB1 = wT + (size_t)(colStart + r1) * K3H_ + kt*32 + c0*8;
    gl_lds16(gA0, As + (size_t)tid * 8);
    gl_lds16(gA1, As + (size_t)(tid + 256) * 8);
    gl_lds16(gB0, Bs + (size_t)tid * 8);
    gl_lds16(gB1, Bs + (size_t)(tid + 256) * 8);
    __syncthreads();
    short8 af[4], bfr[4];
    #pragma unroll
    for (int i = 0; i < 4; ++i){
      af[i]  = *(const short8*)(As + ((wm*64 + i*16 + m16)*32 + quad*8));
      bfr[i] = *(const short8*)(Bs + ((wn*64 + i*16 + m16)*32 + quad*8));
    }
    #pragma unroll
    for (int i = 0; i < 4; ++i)
      #pragma unroll
      for (int j = 0; j < 4; ++j)
        acc[i][j] = __builtin_amdgcn_mfma_f32_16x16x32_bf16(af[i], bfr[j], acc[i][j], 0, 0, 0);
    __syncthreads();
  }
  #pragma unroll
  for (int i = 0; i < 4; ++i)
    #pragma unroll
    for (int j = 0; j < 4; ++j){
      int col = colStart + wn*64 + j*16 + m16;
      float bias = lr_b[col];
      #pragma unroll
      for (int r = 0; r < 4; ++r){
        int row = rowStart + wm*64 + i*16 + quad*4 + r;
        float v = acc[i][j][r] + bias;
        v = v > 0.f ? v : 0.f;
        f_frag[(size_t)row * H_ + col] = f2bf(v);
      }
    }
}

// ---------------- K3: per-batch fused 2-layer attention ----------------
__global__ __launch_bounds__(256) void attn_kernel(
    const unsigned short* __restrict__ f_frag,
    const unsigned short* __restrict__ qkvT, const unsigned short* __restrict__ denseT,
    const float* __restrict__ wq_b, const float* __restrict__ wk_b, const float* __restrict__ wv_b,
    const float* __restrict__ dense_b, const float* __restrict__ ln_g, const float* __restrict__ ln_b,
    unsigned short* __restrict__ hsf, float* __restrict__ out_attn){
  const int HP = 544, TP = 40;
  __shared__ __align__(16) unsigned short hs[S_*544];
  __shared__ __align__(16) unsigned short Qs[S_*40];
  __shared__ __align__(16) unsigned short Ks[S_*40];
  __shared__ __align__(16) unsigned short Vt[S_*40];
  __shared__ __align__(16) unsigned short Ps[S_*40];
  __shared__ __align__(16) unsigned short Xs[S_*40];
  __shared__ unsigned long long pmask[S_*8];
  __shared__ unsigned int mz[S_];
  int b = blockIdx.x;
  int tid = threadIdx.x;
  int wave = tid >> 6, lane = tid & 63;
  int m16 = lane & 15, quad = lane >> 4;

  { // load hs (bf16) from f_frag
    int row = tid >> 3, cc = (tid & 7) * 64;
    const unsigned short* src = f_frag + ((size_t)(b * S_ + row)) * H_ + cc;
    unsigned short* dst = hs + row * HP + cc;
    #pragma unroll
    for (int k = 0; k < 64; k += 8)
      *(uint4*)(dst + k) = *(const uint4*)(src + k);
  }
  if (tid < S_) mz[tid] = 0u;
  __syncthreads();
  { // presence bitmasks
    int s = tid >> 3, w = tid & 7;
    unsigned long long m = 0ull;
    const unsigned short* hrow = hs + s * HP + w * 64;
    for (int j = 0; j < 64; ++j)
      if (hrow[j] != 0) m |= (1ull << j);
    pmask[s * 8 + w] = m;
  }
  __syncthreads();
  for (int idx = tid; idx < S_*S_; idx += 256){
    int s = idx >> 5, t2 = idx & 31;
    bool inter = false;
    #pragma unroll
    for (int w = 0; w < 8; ++w)
      inter = inter || ((pmask[s*8+w] & pmask[t2*8+w]) != 0ull);
    if (!inter) atomicOr(&mz[s], 1u << t2);
  }
  __syncthreads();

  const float scale = 0.17677669529663687f; // 1/sqrt(32)
  for (int l = 0; l < L_; ++l){
    { // (a) QKV: wave -> tile (mt, nt); shared A-frag across the 3 projections
      int mt = wave >> 1, nt = wave & 1;
      floatx4 aq = {0,0,0,0}, ak = {0,0,0,0}, av = {0,0,0,0};
      const unsigned short* arow = hs + (mt*16 + m16) * HP + quad*8;
      const unsigned short* bq = qkvT + ((size_t)((l*3 + 0)*S_ + nt*16 + m16)) * H_ + quad*8;
      const unsigned short* bk = bq + (size_t)S_ * H_;
      const unsigned short* bv = bk + (size_t)S_ * H_;
      for (int k0 = 0; k0 < H_; k0 += 32){
        short8 a = *(const short8*)(arow + k0);
        aq = __builtin_amdgcn_mfma_f32_16x16x32_bf16(a, *(const short8*)(bq + k0), aq, 0,0,0);
        ak = __builtin_amdgcn_mfma_f32_16x16x32_bf16(a, *(const short8*)(bk + k0), ak, 0,0,0);
        av = __builtin_amdgcn_mfma_f32_16x16x32_bf16(a, *(const short8*)(bv + k0), av, 0,0,0);
      }
      int col = nt*16 + m16;
      float bqs = wq_b[l*DK_ + col], bks = wk_b[l*DK_ + col], bvs = wv_b[l*DK_ + col];
      #pragma unroll
      for (int r = 0; r < 4; ++r){
        int rw = mt*16 + quad*4 + r;
        Qs[rw*TP + col] = f2bf((aq[r] + bqs) * scale);
        Ks[rw*TP + col] = f2bf(ak[r] + bks);
        Vt[col*TP + rw] = f2bf(av[r] + bvs);   // transposed store
      }
    }
    __syncthreads();
    if (wave < 2){ // (b) scores + mask + softmax (wave mt handles rows mt*16..+16, all 32 cols)
      int mt = wave;
      short8 a  = *(const short8*)(Qs + (mt*16 + m16)*TP + quad*8);
      short8 b0 = *(const short8*)(Ks + m16*TP + quad*8);
      short8 b1 = *(const short8*)(Ks + (16 + m16)*TP + quad*8);
      floatx4 z = {0,0,0,0};
      floatx4 s0 = __builtin_amdgcn_mfma_f32_16x16x32_bf16(a, b0, z, 0,0,0);
      floatx4 s1 = __builtin_amdgcn_mfma_f32_16x16x32_bf16(a, b1, z, 0,0,0);
      #pragma unroll
      for (int r = 0; r < 4; ++r){
        int s = mt*16 + quad*4 + r;
        unsigned int m = mz[s];
        float v0 = ((m >> m16) & 1u) ? -1e9f : s0[r];
        float v1 = ((m >> (16 + m16)) & 1u) ? -1e9f : s1[r];
        float mx = fmaxf(v0, v1);
        #pragma unroll
        for (int d = 1; d < 16; d <<= 1) mx = fmaxf(mx, __shfl_xor(mx, d));
        float e0 = __expf(v0 - mx), e1 = __expf(v1 - mx);
        float sm = e0 + e1;
        #pragma unroll
        for (int d = 1; d < 16; d <<= 1) sm += __shfl_xor(sm, d);
        float inv = 1.f / sm;
        float p0 = e0 * inv, p1 = e1 * inv;
        Ps[s*TP + m16] = f2bf(p0);
        Ps[s*TP + 16 + m16] = f2bf(p1);
        if (l == L_ - 1){
          float* oa = out_attn + ((size_t)b * S_ + s) * S_;
          oa[m16] = p0; oa[16 + m16] = p1;
        }
      }
    }
    __syncthreads();
    { // (c) X = P @ V
      int mt = wave >> 1, nt = wave & 1;
      short8 a  = *(const short8*)(Ps + (mt*16 + m16)*TP + quad*8);
      short8 bv = *(const short8*)(Vt + (nt*16 + m16)*TP + quad*8);
      floatx4 z = {0,0,0,0};
      floatx4 x = __builtin_amdgcn_mfma_f32_16x16x32_bf16(a, bv, z, 0,0,0);
      #pragma unroll
      for (int r = 0; r < 4; ++r)
        Xs[(mt*16 + quad*4 + r)*TP + nt*16 + m16] = f2bf(x[r]);
    }
    __syncthreads();
    { // (d) dh = X @ dense_w + dense_b + residual, written back into hs (per-lane RMW, no race)
      short8 ax0 = *(const short8*)(Xs + m16*TP + quad*8);
      short8 ax1 = *(const short8*)(Xs + (16 + m16)*TP + quad*8);
      #pragma unroll
      for (int j = 0; j < 8; ++j){
        int col = (wave*8 + j)*16 + m16;
        short8 bw = *(const short8*)(denseT + ((size_t)(l*H_ + col)) * DK_ + quad*8);
        float db = dense_b[l*H_ + col];
        floatx4 z = {0,0,0,0};
        floatx4 d0 = __builtin_amdgcn_mfma_f32_16x16x32_bf16(ax0, bw, z, 0,0,0);
        floatx4 d1 = __builtin_amdgcn_mfma_f32_16x16x32_bf16(ax1, bw, z, 0,0,0);
        #pragma unroll
        for (int r = 0; r < 4; ++r){
          int row0 = quad*4 + r;
          float y0 = d0[r] + db + bf2f(hs[row0*HP + col]);
          hs[row0*HP + col] = f2bf(y0);
          int row1 = 16 + quad*4 + r;
          float y1 = d1[r] + db + bf2f(hs[row1*HP + col]);
          hs[row1*HP + col] = f2bf(y1);
        }
      }
    }
    __syncthreads();
    { // (e) layernorm per row (eps 1e-6), one row per whole wave
      #pragma unroll
      for (int rr = 0; rr < 8; ++rr){
        int row = wave*8 + rr;
        unsigned short* hrow = hs + row*HP + lane*8;
        short8 hv = *(const short8*)hrow;
        float v[8]; float s1 = 0.f, s2 = 0.f;
        #pragma unroll
        for (int j = 0; j < 8; ++j){ v[j] = bf2f((unsigned short)hv[j]); s1 += v[j]; s2 += v[j]*v[j]; }
        #pragma unroll
        for (int d = 1; d < 64; d <<= 1){ s1 += __shfl_xor(s1, d); s2 += __shfl_xor(s2, d); }
        float mean = s1 * (1.f/512.f);
        float var = s2 * (1.f/512.f) - mean*mean;
        float rs = rsqrtf(var + 1e-6f);
        unsigned short o[8] __attribute__((aligned(16)));
        #pragma unroll
        for (int j = 0; j < 8; ++j){
          int colj = lane*8 + j;
          float nv = (v[j] - mean) * rs * ln_g[l*H_ + colj] + ln_b[l*H_ + colj];
          o[j] = f2bf(nv);
        }
        *(uint4*)hrow = *(const uint4*)o;
      }
    }
    __syncthreads();
  }
  if (tid < 64){ // export token-0 row for the final linear
    *(uint4*)(hsf + (size_t)b * H_ + tid*8) = *(const uint4*)(hs + tid*8);
  }
}

// ---------------- K4: f_out = LN(hs0 @ lin_w + lin_b; eps 1e-5) * alpha ----------------
__global__ __launch_bounds__(256) void final_kernel(
    const unsigned short* __restrict__ hsf, const unsigned short* __restrict__ lin_wT,
    const float* __restrict__ lin_b, const float* __restrict__ norm_g, const float* __restrict__ norm_b,
    const float* __restrict__ alpha, float* __restrict__ out_f){
  const int HP = 544;
  __shared__ __align__(16) unsigned short hsb[32*544];
  int blk = blockIdx.x;
  int tid = threadIdx.x;
  int wave = tid >> 6, lane = tid & 63;
  int m16 = lane & 15, quad = lane >> 4;
  { // load 32 rows of hsf
    int row = tid >> 3, cc = (tid & 7) * 64;
    const unsigned short* src = hsf + ((size_t)(blk*32 + row)) * H_ + cc;
    unsigned short* dst = hsb + row*HP + cc;
    #pragma unroll
    for (int k = 0; k < 64; k += 8)
      *(uint4*)(dst + k) = *(const uint4*)(src + k);
  }
  __syncthreads();
  floatx4 acc[2][8];
  #pragma unroll
  for (int mt = 0; mt < 2; ++mt)
    #pragma unroll
    for (int j = 0; j < 8; ++j) acc[mt][j] = (floatx4){0.f,0.f,0.f,0.f};
  for (int k0 = 0; k0 < H_; k0 += 32){
    short8 a0 = *(const short8*)(hsb + m16*HP + k0 + quad*8);
    short8 a1 = *(const short8*)(hsb + (16 + m16)*HP + k0 + quad*8);
    #pragma unroll
    for (int j = 0; j < 8; ++j){
      int n = (wave*8 + j)*16 + m16;
      short8 bw = *(const short8*)(lin_wT + (size_t)n * H_ + k0 + quad*8);
      acc[0][j] = __builtin_amdgcn_mfma_f32_16x16x32_bf16(a0, bw, acc[0][j], 0,0,0);
      acc[1][j] = __builtin_amdgcn_mfma_f32_16x16x32_bf16(a1, bw, acc[1][j], 0,0,0);
    }
  }
  __syncthreads();   // all reads of hsb done before overwrite
  #pragma unroll
  for (int mt = 0; mt < 2; ++mt)
    #pragma unroll
    for (int j = 0; j < 8; ++j){
      int col = (wave*8 + j)*16 + m16;
      float lb = lin_b[col];
      #pragma unroll
      for (int r = 0; r < 4; ++r){
        int row = mt*16 + quad*4 + r;
        hsb[row*HP + col] = f2bf(acc[mt][j][r] + lb);
      }
    }
  __syncthreads();
  float al = alpha[0];
  #pragma unroll
  for (int rr = 0; rr < 8; ++rr){
    int row = wave*8 + rr;
    const unsigned short* hrow = hsb + row*HP + lane*8;
    short8 hv = *(const short8*)hrow;
    float v[8]; float s1 = 0.f, s2 = 0.f;
    #pragma unroll
    for (int j = 0; j < 8; ++j){ v[j] = bf2f((unsigned short)hv[j]); s1 += v[j]; s2 += v[j]*v[j]; }
    #pragma unroll
    for (int d = 1; d < 64; d <<= 1){ s1 += __shfl_xor(s1, d); s2 += __shfl_xor(s2, d); }
    float mean = s1 * (1.f/512.f);
    float var = s2 * (1.f/512.f) - mean*mean;
    float rs = rsqrtf(var + 1e-5f);
    float o[8];
    #pragma unroll
    for (int j = 0; j < 8; ++j){
      int colj = lane*8 + j;
      o[j] = ((v[j] - mean) * rs * norm_g[colj] + norm_b[colj]) * al;
    }
    float* op = out_f + ((size_t)(blk*32 + row)) * H_ + lane*8;
    float4 f0 = {o[0], o[1], o[2], o[3]};
    float4 f1 = {o[4], o[5], o[6], o[7]};
    *(float4*)op = f0;
    *(float4*)(op + 4) = f1;
  }
}

extern "C" void kernel_launch(void* const* d_in, const int* in_sizes, int n_in,
                              void* d_out, int out_size, void* d_ws, size_t ws_size,
                              hipStream_t stream){
  const float* f_atom  = (const float*)d_in[0];
  const float* f_group = (const float*)d_in[1];
  const float* fg      = (const float*)d_in[2];
  const float* alpha   = (const float*)d_in[3];
  const float* lr_w    = (const float*)d_in[4];
  const float* lr_b    = (const float*)d_in[5];
  const float* wq_w    = (const float*)d_in[6];
  const float* wq_b    = (const float*)d_in[7];
  const float* wk_w    = (const float*)d_in[8];
  const float* wk_b    = (const float*)d_in[9];
  const float* wv_w    = (const float*)d_in[10];
  const float* wv_b    = (const float*)d_in[11];
  const float* dense_w = (const float*)d_in[12];
  const float* dense_b = (const float*)d_in[13];
  const float* ln_g    = (const float*)d_in[14];
  const float* ln_b    = (const float*)d_in[15];
  const float* lin_w   = (const float*)d_in[16];
  const float* lin_b   = (const float*)d_in[17];
  const float* norm_g  = (const float*)d_in[18];
  const float* norm_b  = (const float*)d_in[19];
  const int*   mapping = (const int*)d_in[20];

  unsigned short* brics  = (unsigned short*)d_ws;                  // 32768*1536
  unsigned short* f_frag = brics  + (size_t)32768 * 1536;          // 32768*512
  unsigned short* lr_wT  = f_frag + (size_t)32768 * 512;           // 512*1536
  unsigned short* qkvT   = lr_wT  + (size_t)512 * 1536;            // 2*3*32*512
  unsigned short* denseT = qkvT   + (size_t)2*3*32*512;            // 2*512*32
  unsigned short* lin_wT = denseT + (size_t)2*512*32;              // 512*512
  unsigned short* hsf    = lin_wT + (size_t)512*512;               // 1024*512

  float* out_f    = (float*)d_out;
  float* out_attn = out_f + (size_t)B_ * H_;

  prep_weights<<<4608, 256, 0, stream>>>(lr_w, wq_w, wk_w, wv_w, dense_w, lin_w,
                                         lr_wT, qkvT, denseT, lin_wT);
  build_brics<<<B_ * S_, 64, 0, stream>>>(f_atom, f_group, fg, mapping, brics);
  gemm_frag<<<(32768/128) * (512/128), 256, 0, stream>>>(brics, lr_wT, lr_b, f_frag);
  attn_kernel<<<B_, 256, 0, stream>>>(f_frag, qkvT, denseT, wq_b, wk_b, wv_b,
                                      dense_b, ln_g, ln_b, hsf, out_attn);
  final_kernel<<<B_/32, 256, 0, stream>>>(hsf, lin_wT, lin_b, norm_g, norm_b, alpha, out_f);
}

// Round 2
// 502.609 us; speedup vs baseline: 1.0237x; 1.0237x over previous
//
#include <hip/hip_runtime.h>

#define B_   1024
#define A_   64
#define G_   31
#define W_   8
#define H_   512
#define L_   2
#define S_   32
#define DK_  32
#define K3H_ 1536

typedef short short8 __attribute__((ext_vector_type(8)));
typedef float floatx4 __attribute__((ext_vector_type(4)));

__device__ __forceinline__ float bf2f(unsigned short u){
  union { unsigned int i; float f; } x; x.i = ((unsigned int)u) << 16; return x.f;
}
__device__ __forceinline__ unsigned short f2bf(float f){
  union { float f; unsigned int i; } x; x.f = f;
  unsigned int u = x.i;
  return (unsigned short)((u + 0x7FFFu + ((u >> 16) & 1u)) >> 16);
}
__device__ __forceinline__ void gl_lds16(const unsigned short* g, unsigned short* l){
  __builtin_amdgcn_global_load_lds((const __attribute__((address_space(1))) unsigned int*)g,
                                   (__attribute__((address_space(3))) unsigned int*)l, 16, 0, 0);
}

// ---------------- K0a: LDS-tiled transpose+convert for lr_w and lin_w ----------------
// src[R][C] f32 -> dst[C][R] bf16, 64x64 tiles. grid: 192 (lr_w, R=1536 C=512) + 64 (lin_w, 512x512)
__global__ __launch_bounds__(256) void prep_transpose(
    const float* __restrict__ lr_w, const float* __restrict__ lin_w,
    unsigned short* __restrict__ lr_wT, unsigned short* __restrict__ lin_wT){
  __shared__ float tile[64][65];
  int bx = blockIdx.x;
  const float* src; unsigned short* dst; int R, C;
  if (bx < 192){ src = lr_w;  dst = lr_wT;  R = 1536; C = 512; }
  else         { bx -= 192; src = lin_w; dst = lin_wT; R = 512;  C = 512; }
  int rt = bx >> 3, ct = bx & 7;     // C/64 == 8 for both
  int tid = threadIdx.x;
  int r16 = tid >> 4, c4 = tid & 15;
  #pragma unroll
  for (int p = 0; p < 4; ++p){
    int row = p*16 + r16;
    float4 v = *(const float4*)(src + (size_t)(rt*64 + row) * C + ct*64 + c4*4);
    tile[row][c4*4+0] = v.x; tile[row][c4*4+1] = v.y;
    tile[row][c4*4+2] = v.z; tile[row][c4*4+3] = v.w;
  }
  __syncthreads();
  int rr = tid >> 3, cc8 = tid & 7;
  #pragma unroll
  for (int p = 0; p < 2; ++p){
    int n = p*32 + rr;
    unsigned short o[8] __attribute__((aligned(16)));
    #pragma unroll
    for (int j = 0; j < 8; ++j) o[j] = f2bf(tile[cc8*8 + j][n]);
    *(uint4*)(dst + (size_t)(ct*64 + n) * R + rt*64 + cc8*8) = *(const uint4*)o;
  }
}

// ---------------- K0b: small scatter convert for qkvT / denseT ----------------
// qkvT[l][p][n(32)][k(512)], denseT[l][n(512)][k(32)]
__global__ __launch_bounds__(256) void prep_small(
    const float* __restrict__ wq_w, const float* __restrict__ wk_w, const float* __restrict__ wv_w,
    const float* __restrict__ dense_w,
    unsigned short* __restrict__ qkvT, unsigned short* __restrict__ denseT){
  int i = blockIdx.x * 256 + threadIdx.x;
  if (i < 98304){                        // qkvT
    int k = i & 511; int t = i >> 9; int n = t & 31; int u = t >> 5;
    int p = u % 3, l = u / 3;
    const float* src = (p == 0) ? wq_w : (p == 1) ? wk_w : wv_w;
    qkvT[((size_t)((l*3+p)*S_ + n)) * H_ + k] = f2bf(src[((size_t)(l*H_ + k)) * DK_ + n]);
    return;
  }
  i -= 98304;                            // denseT (32768)
  int k = i & 31; int t = i >> 5; int n = t & 511; int l = t >> 9;
  denseT[((size_t)(l*H_ + n)) * DK_ + k] = f2bf(dense_w[((size_t)(l*DK_ + k)) * H_ + n]);
}

// ---------------- K1: build brics rows; 4 groups per 256-thread block ----------------
__global__ __launch_bounds__(256) void build_brics(
    const float* __restrict__ f_atom, const float* __restrict__ f_group,
    const float* __restrict__ fg, const int* __restrict__ mapping,
    unsigned short* __restrict__ brics){
  int pair = blockIdx.x * 4 + (threadIdx.x >> 6);   // b*32 + s
  int b = pair >> 5, s = pair & 31;
  int t = threadIdx.x & 63;
  unsigned short* out = brics + (size_t)pair * K3H_;
  if (s == 0){
    for (int k = t; k < K3H_; k += 64) out[k] = f2bf(fg[k]);
    return;
  }
  int g = s - 1;
  const int* mp = mapping + ((size_t)(b * G_ + g)) * W_;
  int c0 = t * 8;
  float sum[8], mx[8];
  #pragma unroll
  for (int j = 0; j < 8; ++j){ sum[j] = 0.f; mx[j] = -3.4e38f; }
  for (int w = 0; w < W_; ++w){
    int idx = mp[w];
    if (idx == 0){
      #pragma unroll
      for (int j = 0; j < 8; ++j) mx[j] = fmaxf(mx[j], 0.f);
    } else {
      const float* row = f_atom + ((size_t)(b * A_ + idx - 1)) * H_ + c0;
      float4 v0 = *(const float4*)row;
      float4 v1 = *(const float4*)(row + 4);
      float v[8] = {v0.x,v0.y,v0.z,v0.w,v1.x,v1.y,v1.z,v1.w};
      #pragma unroll
      for (int j = 0; j < 8; ++j){ sum[j] += v[j]; mx[j] = fmaxf(mx[j], v[j]); }
    }
  }
  const float* grow = f_group + ((size_t)(b * G_ + g)) * H_ + c0;
  float4 g0 = *(const float4*)grow;
  float4 g1 = *(const float4*)(grow + 4);
  float gv[8] = {g0.x,g0.y,g0.z,g0.w,g1.x,g1.y,g1.z,g1.w};
  unsigned short tmp[8] __attribute__((aligned(16)));
  #pragma unroll
  for (int j = 0; j < 8; ++j) tmp[j] = f2bf(sum[j]);
  *(uint4*)(out + c0) = *(const uint4*)tmp;
  #pragma unroll
  for (int j = 0; j < 8; ++j) tmp[j] = f2bf(mx[j]);
  *(uint4*)(out + 512 + c0) = *(const uint4*)tmp;
  #pragma unroll
  for (int j = 0; j < 8; ++j) tmp[j] = f2bf(gv[j]);
  *(uint4*)(out + 1024 + c0) = *(const uint4*)tmp;
}

// ---------------- K2: f_frag = relu(brics @ lr_w + lr_b) ----------------
// 128x128 tile, BK=64, XOR bank-swizzle, XCD-aware block swizzle.
__global__ __launch_bounds__(256) void gemm_frag(
    const unsigned short* __restrict__ brics, const unsigned short* __restrict__ wT,
    const float* __restrict__ lr_b, unsigned short* __restrict__ f_frag){
  __shared__ __align__(16) unsigned short As[128*64];
  __shared__ __align__(16) unsigned short Bs[128*64];
  int tid = threadIdx.x;
  int bx = blockIdx.x;
  // XCD swizzle: all 4 ntiles of one mtile land on the same XCD (bx%8 -> XCD).
  int xcd = bx & 7, slot = bx >> 3;          // slot in 0..127
  int mtile = xcd + 8 * (slot >> 2);         // 32 mtiles per XCD
  int ntile = slot & 3;
  int rowStart = mtile * 128, colStart = ntile * 128;
  int lane = tid & 63, wave = tid >> 6;
  int m16 = lane & 15, quad = lane >> 4;
  int wm = wave >> 1, wn = wave & 1;
  floatx4 acc[4][4];
  #pragma unroll
  for (int i = 0; i < 4; ++i)
    #pragma unroll
    for (int j = 0; j < 4; ++j) acc[i][j] = (floatx4){0.f,0.f,0.f,0.f};

  // staging map: pass p stages rows p*32 + (tid>>3); LDS chunk tid&7 holds
  // global chunk (tid&7) ^ (srow&7)  -> swizzled LDS layout, lane-linear dst.
  int srow = tid >> 3;
  int gchunk = (tid & 7) ^ (srow & 7);
  size_t aOff[4], bOff[4];
  #pragma unroll
  for (int p = 0; p < 4; ++p){
    aOff[p] = (size_t)(rowStart + p*32 + srow) * K3H_ + gchunk*8;
    bOff[p] = (size_t)(colStart + p*32 + srow) * K3H_ + gchunk*8;
  }
  // fragment-read swizzled chunk offsets (in shorts): chunk_sw = (ks*4+quad) ^ (m16&7)
  int fsw0 = ((0*4 + quad) ^ (m16 & 7)) * 8;
  int fsw1 = ((1*4 + quad) ^ (m16 & 7)) * 8;

  for (int kt = 0; kt < K3H_/64; ++kt){
    int kbase = kt * 64;
    #pragma unroll
    for (int p = 0; p < 4; ++p){
      gl_lds16(brics + aOff[p] + kbase, As + p*2048 + (size_t)tid*8);
      gl_lds16(wT    + bOff[p] + kbase, Bs + p*2048 + (size_t)tid*8);
    }
    __syncthreads();
    #pragma unroll
    for (int ks = 0; ks < 2; ++ks){
      int fsw = ks ? fsw1 : fsw0;
      short8 af[4], bfr[4];
      #pragma unroll
      for (int i = 0; i < 4; ++i){
        af[i]  = *(const short8*)(As + (wm*64 + i*16 + m16)*64 + fsw);
        bfr[i] = *(const short8*)(Bs + (wn*64 + i*16 + m16)*64 + fsw);
      }
      #pragma unroll
      for (int i = 0; i < 4; ++i)
        #pragma unroll
        for (int j = 0; j < 4; ++j)
          acc[i][j] = __builtin_amdgcn_mfma_f32_16x16x32_bf16(af[i], bfr[j], acc[i][j], 0, 0, 0);
    }
    __syncthreads();
  }
  #pragma unroll
  for (int i = 0; i < 4; ++i)
    #pragma unroll
    for (int j = 0; j < 4; ++j){
      int col = colStart + wn*64 + j*16 + m16;
      float bias = lr_b[col];
      #pragma unroll
      for (int r = 0; r < 4; ++r){
        int row = rowStart + wm*64 + i*16 + quad*4 + r;
        float v = acc[i][j][r] + bias;
        v = v > 0.f ? v : 0.f;
        f_frag[(size_t)row * H_ + col] = f2bf(v);
      }
    }
}

// ---------------- K3: per-batch fused 2-layer attention ----------------
__global__ __launch_bounds__(256) void attn_kernel(
    const unsigned short* __restrict__ f_frag,
    const unsigned short* __restrict__ qkvT, const unsigned short* __restrict__ denseT,
    const float* __restrict__ wq_b, const float* __restrict__ wk_b, const float* __restrict__ wv_b,
    const float* __restrict__ dense_b, const float* __restrict__ ln_g, const float* __restrict__ ln_b,
    unsigned short* __restrict__ hsf, float* __restrict__ out_attn){
  const int HP = 544, TP = 40;
  __shared__ __align__(16) unsigned short hs[S_*544];
  __shared__ __align__(16) unsigned short Qs[S_*40];
  __shared__ __align__(16) unsigned short Ks[S_*40];
  __shared__ __align__(16) unsigned short Vt[S_*40];
  __shared__ __align__(16) unsigned short Ps[S_*40];
  __shared__ __align__(16) unsigned short Xs[S_*40];
  __shared__ unsigned long long pmask[S_*8];
  __shared__ unsigned int mz[S_];
  int b = blockIdx.x;
  int tid = threadIdx.x;
  int wave = tid >> 6, lane = tid & 63;
  int m16 = lane & 15, quad = lane >> 4;

  { // load hs (bf16) from f_frag
    int row = tid >> 3, cc = (tid & 7) * 64;
    const unsigned short* src = f_frag + ((size_t)(b * S_ + row)) * H_ + cc;
    unsigned short* dst = hs + row * HP + cc;
    #pragma unroll
    for (int k = 0; k < 64; k += 8)
      *(uint4*)(dst + k) = *(const uint4*)(src + k);
  }
  if (tid < S_) mz[tid] = 0u;
  __syncthreads();
  { // presence bitmasks
    int s = tid >> 3, w = tid & 7;
    unsigned long long m = 0ull;
    const unsigned short* hrow = hs + s * HP + w * 64;
    for (int j = 0; j < 64; ++j)
      if (hrow[j] != 0) m |= (1ull << j);
    pmask[s * 8 + w] = m;
  }
  __syncthreads();
  for (int idx = tid; idx < S_*S_; idx += 256){
    int s = idx >> 5, t2 = idx & 31;
    bool inter = false;
    #pragma unroll
    for (int w = 0; w < 8; ++w)
      inter = inter || ((pmask[s*8+w] & pmask[t2*8+w]) != 0ull);
    if (!inter) atomicOr(&mz[s], 1u << t2);
  }
  __syncthreads();

  const float scale = 0.17677669529663687f; // 1/sqrt(32)
  for (int l = 0; l < L_; ++l){
    { // (a) QKV
      int mt = wave >> 1, nt = wave & 1;
      floatx4 aq = {0,0,0,0}, ak = {0,0,0,0}, av = {0,0,0,0};
      const unsigned short* arow = hs + (mt*16 + m16) * HP + quad*8;
      const unsigned short* bq = qkvT + ((size_t)((l*3 + 0)*S_ + nt*16 + m16)) * H_ + quad*8;
      const unsigned short* bk = bq + (size_t)S_ * H_;
      const unsigned short* bv = bk + (size_t)S_ * H_;
      for (int k0 = 0; k0 < H_; k0 += 32){
        short8 a = *(const short8*)(arow + k0);
        aq = __builtin_amdgcn_mfma_f32_16x16x32_bf16(a, *(const short8*)(bq + k0), aq, 0,0,0);
        ak = __builtin_amdgcn_mfma_f32_16x16x32_bf16(a, *(const short8*)(bk + k0), ak, 0,0,0);
        av = __builtin_amdgcn_mfma_f32_16x16x32_bf16(a, *(const short8*)(bv + k0), av, 0,0,0);
      }
      int col = nt*16 + m16;
      float bqs = wq_b[l*DK_ + col], bks = wk_b[l*DK_ + col], bvs = wv_b[l*DK_ + col];
      #pragma unroll
      for (int r = 0; r < 4; ++r){
        int rw = mt*16 + quad*4 + r;
        Qs[rw*TP + col] = f2bf((aq[r] + bqs) * scale);
        Ks[rw*TP + col] = f2bf(ak[r] + bks);
        Vt[col*TP + rw] = f2bf(av[r] + bvs);   // transposed store
      }
    }
    __syncthreads();
    if (wave < 2){ // (b) scores + mask + softmax
      int mt = wave;
      short8 a  = *(const short8*)(Qs + (mt*16 + m16)*TP + quad*8);
      short8 b0 = *(const short8*)(Ks + m16*TP + quad*8);
      short8 b1 = *(const short8*)(Ks + (16 + m16)*TP + quad*8);
      floatx4 z = {0,0,0,0};
      floatx4 s0 = __builtin_amdgcn_mfma_f32_16x16x32_bf16(a, b0, z, 0,0,0);
      floatx4 s1 = __builtin_amdgcn_mfma_f32_16x16x32_bf16(a, b1, z, 0,0,0);
      #pragma unroll
      for (int r = 0; r < 4; ++r){
        int s = mt*16 + quad*4 + r;
        unsigned int m = mz[s];
        float v0 = ((m >> m16) & 1u) ? -1e9f : s0[r];
        float v1 = ((m >> (16 + m16)) & 1u) ? -1e9f : s1[r];
        float mx = fmaxf(v0, v1);
        #pragma unroll
        for (int d = 1; d < 16; d <<= 1) mx = fmaxf(mx, __shfl_xor(mx, d));
        float e0 = __expf(v0 - mx), e1 = __expf(v1 - mx);
        float sm = e0 + e1;
        #pragma unroll
        for (int d = 1; d < 16; d <<= 1) sm += __shfl_xor(sm, d);
        float inv = 1.f / sm;
        float p0 = e0 * inv, p1 = e1 * inv;
        Ps[s*TP + m16] = f2bf(p0);
        Ps[s*TP + 16 + m16] = f2bf(p1);
        if (l == L_ - 1){
          float* oa = out_attn + ((size_t)b * S_ + s) * S_;
          oa[m16] = p0; oa[16 + m16] = p1;
        }
      }
    }
    __syncthreads();
    { // (c) X = P @ V
      int mt = wave >> 1, nt = wave & 1;
      short8 a  = *(const short8*)(Ps + (mt*16 + m16)*TP + quad*8);
      short8 bv = *(const short8*)(Vt + (nt*16 + m16)*TP + quad*8);
      floatx4 z = {0,0,0,0};
      floatx4 x = __builtin_amdgcn_mfma_f32_16x16x32_bf16(a, bv, z, 0,0,0);
      #pragma unroll
      for (int r = 0; r < 4; ++r)
        Xs[(mt*16 + quad*4 + r)*TP + nt*16 + m16] = f2bf(x[r]);
    }
    __syncthreads();
    { // (d) dh = X @ dense_w + dense_b + residual
      short8 ax0 = *(const short8*)(Xs + m16*TP + quad*8);
      short8 ax1 = *(const short8*)(Xs + (16 + m16)*TP + quad*8);
      #pragma unroll
      for (int j = 0; j < 8; ++j){
        int col = (wave*8 + j)*16 + m16;
        short8 bw = *(const short8*)(denseT + ((size_t)(l*H_ + col)) * DK_ + quad*8);
        float db = dense_b[l*H_ + col];
        floatx4 z = {0,0,0,0};
        floatx4 d0 = __builtin_amdgcn_mfma_f32_16x16x32_bf16(ax0, bw, z, 0,0,0);
        floatx4 d1 = __builtin_amdgcn_mfma_f32_16x16x32_bf16(ax1, bw, z, 0,0,0);
        #pragma unroll
        for (int r = 0; r < 4; ++r){
          int row0 = quad*4 + r;
          float y0 = d0[r] + db + bf2f(hs[row0*HP + col]);
          hs[row0*HP + col] = f2bf(y0);
          int row1 = 16 + quad*4 + r;
          float y1 = d1[r] + db + bf2f(hs[row1*HP + col]);
          hs[row1*HP + col] = f2bf(y1);
        }
      }
    }
    __syncthreads();
    { // (e) layernorm per row (eps 1e-6)
      #pragma unroll
      for (int rr = 0; rr < 8; ++rr){
        int row = wave*8 + rr;
        unsigned short* hrow = hs + row*HP + lane*8;
        short8 hv = *(const short8*)hrow;
        float v[8]; float s1 = 0.f, s2 = 0.f;
        #pragma unroll
        for (int j = 0; j < 8; ++j){ v[j] = bf2f((unsigned short)hv[j]); s1 += v[j]; s2 += v[j]*v[j]; }
        #pragma unroll
        for (int d = 1; d < 64; d <<= 1){ s1 += __shfl_xor(s1, d); s2 += __shfl_xor(s2, d); }
        float mean = s1 * (1.f/512.f);
        float var = s2 * (1.f/512.f) - mean*mean;
        float rs = rsqrtf(var + 1e-6f);
        unsigned short o[8] __attribute__((aligned(16)));
        #pragma unroll
        for (int j = 0; j < 8; ++j){
          int colj = lane*8 + j;
          float nv = (v[j] - mean) * rs * ln_g[l*H_ + colj] + ln_b[l*H_ + colj];
          o[j] = f2bf(nv);
        }
        *(uint4*)hrow = *(const uint4*)o;
      }
    }
    __syncthreads();
  }
  if (tid < 64){
    *(uint4*)(hsf + (size_t)b * H_ + tid*8) = *(const uint4*)(hs + tid*8);
  }
}

// ---------------- K4: f_out = LN(hs0 @ lin_w + lin_b; eps 1e-5) * alpha ----------------
__global__ __launch_bounds__(256) void final_kernel(
    const unsigned short* __restrict__ hsf, const unsigned short* __restrict__ lin_wT,
    const float* __restrict__ lin_b, const float* __restrict__ norm_g, const float* __restrict__ norm_b,
    const float* __restrict__ alpha, float* __restrict__ out_f){
  const int HP = 544;
  __shared__ __align__(16) unsigned short hsb[32*544];
  int blk = blockIdx.x;
  int tid = threadIdx.x;
  int wave = tid >> 6, lane = tid & 63;
  int m16 = lane & 15, quad = lane >> 4;
  {
    int row = tid >> 3, cc = (tid & 7) * 64;
    const unsigned short* src = hsf + ((size_t)(blk*32 + row)) * H_ + cc;
    unsigned short* dst = hsb + row*HP + cc;
    #pragma unroll
    for (int k = 0; k < 64; k += 8)
      *(uint4*)(dst + k) = *(const uint4*)(src + k);
  }
  __syncthreads();
  floatx4 acc[2][8];
  #pragma unroll
  for (int mt = 0; mt < 2; ++mt)
    #pragma unroll
    for (int j = 0; j < 8; ++j) acc[mt][j] = (floatx4){0.f,0.f,0.f,0.f};
  for (int k0 = 0; k0 < H_; k0 += 32){
    short8 a0 = *(const short8*)(hsb + m16*HP + k0 + quad*8);
    short8 a1 = *(const short8*)(hsb + (16 + m16)*HP + k0 + quad*8);
    #pragma unroll
    for (int j = 0; j < 8; ++j){
      int n = (wave*8 + j)*16 + m16;
      short8 bw = *(const short8*)(lin_wT + (size_t)n * H_ + k0 + quad*8);
      acc[0][j] = __builtin_amdgcn_mfma_f32_16x16x32_bf16(a0, bw, acc[0][j], 0,0,0);
      acc[1][j] = __builtin_amdgcn_mfma_f32_16x16x32_bf16(a1, bw, acc[1][j], 0,0,0);
    }
  }
  __syncthreads();
  #pragma unroll
  for (int mt = 0; mt < 2; ++mt)
    #pragma unroll
    for (int j = 0; j < 8; ++j){
      int col = (wave*8 + j)*16 + m16;
      float lb = lin_b[col];
      #pragma unroll
      for (int r = 0; r < 4; ++r){
        int row = mt*16 + quad*4 + r;
        hsb[row*HP + col] = f2bf(acc[mt][j][r] + lb);
      }
    }
  __syncthreads();
  float al = alpha[0];
  #pragma unroll
  for (int rr = 0; rr < 8; ++rr){
    int row = wave*8 + rr;
    const unsigned short* hrow = hsb + row*HP + lane*8;
    short8 hv = *(const short8*)hrow;
    float v[8]; float s1 = 0.f, s2 = 0.f;
    #pragma unroll
    for (int j = 0; j < 8; ++j){ v[j] = bf2f((unsigned short)hv[j]); s1 += v[j]; s2 += v[j]*v[j]; }
    #pragma unroll
    for (int d = 1; d < 64; d <<= 1){ s1 += __shfl_xor(s1, d); s2 += __shfl_xor(s2, d); }
    float mean = s1 * (1.f/512.f);
    float var = s2 * (1.f/512.f) - mean*mean;
    float rs = rsqrtf(var + 1e-5f);
    float o[8];
    #pragma unroll
    for (int j = 0; j < 8; ++j){
      int colj = lane*8 + j;
      o[j] = ((v[j] - mean) * rs * norm_g[colj] + norm_b[colj]) * al;
    }
    float* op = out_f + ((size_t)(blk*32 + row)) * H_ + lane*8;
    float4 f0 = {o[0], o[1], o[2], o[3]};
    float4 f1 = {o[4], o[5], o[6], o[7]};
    *(float4*)op = f0;
    *(float4*)(op + 4) = f1;
  }
}

extern "C" void kernel_launch(void* const* d_in, const int* in_sizes, int n_in,
                              void* d_out, int out_size, void* d_ws, size_t ws_size,
                              hipStream_t stream){
  const float* f_atom  = (const float*)d_in[0];
  const float* f_group = (const float*)d_in[1];
  const float* fg      = (const float*)d_in[2];
  const float* alpha   = (const float*)d_in[3];
  const float* lr_w    = (const float*)d_in[4];
  const float* lr_b    = (const float*)d_in[5];
  const float* wq_w    = (const float*)d_in[6];
  const float* wq_b    = (const float*)d_in[7];
  const float* wk_w    = (const float*)d_in[8];
  const float* wk_b    = (const float*)d_in[9];
  const float* wv_w    = (const float*)d_in[10];
  const float* wv_b    = (const float*)d_in[11];
  const float* dense_w = (const float*)d_in[12];
  const float* dense_b = (const float*)d_in[13];
  const float* ln_g    = (const float*)d_in[14];
  const float* ln_b    = (const float*)d_in[15];
  const float* lin_w   = (const float*)d_in[16];
  const float* lin_b   = (const float*)d_in[17];
  const float* norm_g  = (const float*)d_in[18];
  const float* norm_b  = (const float*)d_in[19];
  const int*   mapping = (const int*)d_in[20];

  unsigned short* brics  = (unsigned short*)d_ws;                  // 32768*1536
  unsigned short* f_frag = brics  + (size_t)32768 * 1536;          // 32768*512
  unsigned short* lr_wT  = f_frag + (size_t)32768 * 512;           // 512*1536
  unsigned short* qkvT   = lr_wT  + (size_t)512 * 1536;            // 2*3*32*512
  unsigned short* denseT = qkvT   + (size_t)2*3*32*512;            // 2*512*32
  unsigned short* lin_wT = denseT + (size_t)2*512*32;              // 512*512
  unsigned short* hsf    = lin_wT + (size_t)512*512;               // 1024*512

  float* out_f    = (float*)d_out;
  float* out_attn = out_f + (size_t)B_ * H_;

  prep_transpose<<<256, 256, 0, stream>>>(lr_w, lin_w, lr_wT, lin_wT);
  prep_small<<<512, 256, 0, stream>>>(wq_w, wk_w, wv_w, dense_w, qkvT, denseT);
  build_brics<<<B_ * S_ / 4, 256, 0, stream>>>(f_atom, f_group, fg, mapping, brics);
  gemm_frag<<<(32768/128) * (512/128), 256, 0, stream>>>(brics, lr_wT, lr_b, f_frag);
  attn_kernel<<<B_, 256, 0, stream>>>(f_frag, qkvT, denseT, wq_b, wk_b, wv_b,
                                      dense_b, ln_g, ln_b, hsf, out_attn);
  final_kernel<<<B_/32, 256, 0, stream>>>(hsf, lin_wT, lin_b, norm_g, norm_b, alpha, out_f);
}